// Round 2
// baseline (562.346 us; speedup 1.0000x reference)
//
#include <hip/hip_runtime.h>

#define DEV __device__ __forceinline__

DEV float lrelu(float v) { return v > 0.f ? v : 0.2f * v; }
DEV float4 ld4(const float* p) { return *reinterpret_cast<const float4*>(p); }

// ---------------- CSR build ----------------
__global__ void hist_kernel(const int* __restrict__ ei, int E, int* __restrict__ cnt) {
  int e = blockIdx.x * blockDim.x + threadIdx.x;
  if (e < E) atomicAdd(&cnt[ei[E + e]], 1);
}

// single-block scan (cnt may alias cursor; no __restrict__ here on purpose)
__global__ __launch_bounds__(1024) void scan_kernel(const int* cnt, int N,
                                                    int* row_ptr, int* cursor) {
  __shared__ int wsum[16];
  __shared__ int s_carry;
  const int tid = threadIdx.x;
  const int lane = tid & 63;
  const int wid = tid >> 6;
  if (tid == 0) s_carry = 0;
  __syncthreads();
  for (int base = 0; base < N; base += 1024) {
    int i = base + tid;
    int v = (i < N) ? cnt[i] : 0;
    int x = v;
    #pragma unroll
    for (int off = 1; off < 64; off <<= 1) {
      int y = __shfl_up(x, off);
      if (lane >= off) x += y;
    }
    if (lane == 63) wsum[wid] = x;
    __syncthreads();
    int woff = 0;
    for (int ww = 0; ww < wid; ++ww) woff += wsum[ww];
    int carry = s_carry;
    int incl = carry + woff + x;
    if (i < N) { row_ptr[i] = incl - v; cursor[i] = incl - v; }
    __syncthreads();
    if (tid == 1023) s_carry = incl;
    __syncthreads();
  }
  if (tid == 0) row_ptr[N] = s_carry;
}

__global__ void scatter_kernel(const int* __restrict__ ei, int E,
                               int* __restrict__ cursor,
                               int* __restrict__ csr_src, int* __restrict__ csr_dst) {
  int e = blockIdx.x * blockDim.x + threadIdx.x;
  if (e >= E) return;
  int s = ei[e], d = ei[E + e];
  int pos = atomicAdd(&cursor[d], 1);
  csr_src[pos] = s;
  csr_dst[pos] = d;
}

// ---------------- fused dual GEMM: Xl = A*Wl+bl, Xr = A*Wr+br ----------------
// A: [N,K] row-major, Wl/Wr: [K,64], outputs [N,64]
template <int K>
__global__ __launch_bounds__(256) void gemm_dual(
    const float* __restrict__ A, int N,
    const float* __restrict__ Wl, const float* __restrict__ bl,
    const float* __restrict__ Wr, const float* __restrict__ br,
    float* __restrict__ Xl, float* __restrict__ Xr) {
  constexpr int KC = 32;
  constexpr int BR = 128;
  constexpr int LDA = BR + 4;   // 132 -> keeps float4 alignment (528 B row stride)
  constexpr int LDW = 128 + 4;  // 132
  __shared__ float sA[KC][LDA];   // A transposed: [k][row]
  __shared__ float sW[KC][LDW];   // [k][col] (cols 0..63 = Wl, 64..127 = Wr)
  const int tid = threadIdx.x;
  const int rb = blockIdx.x * BR;
  const int rowg = tid >> 4;  // 0..15 -> rows rowg*8..+7
  const int colg = tid & 15;  // 0..15 -> cols colg*8..+7
  float acc[8][8];
  #pragma unroll
  for (int i = 0; i < 8; ++i)
    #pragma unroll
    for (int j = 0; j < 8; ++j) acc[i][j] = 0.f;

  for (int kc = 0; kc < K; kc += KC) {
    // stage W (32 x 128 floats)
    #pragma unroll
    for (int rep = 0; rep < 4; ++rep) {
      int lin = rep * 1024 + tid * 4;
      int k = lin >> 7, j = lin & 127;
      const float* src = (j < 64) ? (Wl + (size_t)(kc + k) * 64 + j)
                                  : (Wr + (size_t)(kc + k) * 64 + (j - 64));
      *reinterpret_cast<float4*>(&sW[k][j]) = ld4(src);
    }
    // stage A transposed (128 rows x 32 k)
    #pragma unroll
    for (int rep = 0; rep < 4; ++rep) {
      int lin = rep * 1024 + tid * 4;
      int r = lin >> 5;      // 0..127
      int kk = lin & 31;     // multiple of 4
      int row = rb + r;
      if (row >= N) row = N - 1;
      float4 v = ld4(A + (size_t)row * K + kc + kk);
      sA[kk + 0][r] = v.x;
      sA[kk + 1][r] = v.y;
      sA[kk + 2][r] = v.z;
      sA[kk + 3][r] = v.w;
    }
    __syncthreads();
    #pragma unroll
    for (int k = 0; k < KC; ++k) {
      float a[8], wv[8];
      *reinterpret_cast<float4*>(&a[0]) = *reinterpret_cast<const float4*>(&sA[k][rowg * 8]);
      *reinterpret_cast<float4*>(&a[4]) = *reinterpret_cast<const float4*>(&sA[k][rowg * 8 + 4]);
      *reinterpret_cast<float4*>(&wv[0]) = *reinterpret_cast<const float4*>(&sW[k][colg * 8]);
      *reinterpret_cast<float4*>(&wv[4]) = *reinterpret_cast<const float4*>(&sW[k][colg * 8 + 4]);
      #pragma unroll
      for (int i = 0; i < 8; ++i)
        #pragma unroll
        for (int j = 0; j < 8; ++j) acc[i][j] = fmaf(a[i], wv[j], acc[i][j]);
    }
    __syncthreads();
  }
  // epilogue
  const int cb = colg * 8;
  float bv[8];
  #pragma unroll
  for (int j = 0; j < 8; ++j) bv[j] = (cb < 64) ? bl[cb + j] : br[cb - 64 + j];
  #pragma unroll
  for (int i = 0; i < 8; ++i) {
    int row = rb + rowg * 8 + i;
    if (row < N) {
      float o[8];
      #pragma unroll
      for (int j = 0; j < 8; ++j) o[j] = acc[i][j] + bv[j];
      float* dst = (cb < 64) ? (Xl + (size_t)row * 64 + cb) : (Xr + (size_t)row * 64 + cb - 64);
      *reinterpret_cast<float4*>(dst) = make_float4(o[0], o[1], o[2], o[3]);
      *reinterpret_cast<float4*>(dst + 4) = make_float4(o[4], o[5], o[6], o[7]);
    }
  }
}

// ---------------- conv1 edge attention logits (H=4, C=16) ----------------
__global__ void edge_e1_kernel(const int* __restrict__ csr_src, const int* __restrict__ csr_dst,
                               int E, int N,
                               const float* __restrict__ xl, const float* __restrict__ xr,
                               const float* __restrict__ att,
                               float* __restrict__ e_csr, float* __restrict__ e_self) {
  int t = blockIdx.x * blockDim.x + threadIdx.x;
  int pos = t >> 2, h = t & 3;
  if (pos >= E + N) return;
  int s, d;
  float* outp;
  if (pos < E) {
    s = csr_src[pos]; d = csr_dst[pos];
    outp = e_csr + (size_t)pos * 4 + h;
  } else {
    int n = pos - E; s = n; d = n;
    outp = e_self + (size_t)n * 4 + h;
  }
  const float* pa = xl + (size_t)s * 64 + h * 16;
  const float* pb = xr + (size_t)d * 64 + h * 16;
  const float* pw = att + h * 16;
  float acc = 0.f;
  #pragma unroll
  for (int q = 0; q < 4; ++q) {
    float4 a = ld4(pa + q * 4), b = ld4(pb + q * 4), w = ld4(pw + q * 4);
    acc += lrelu(a.x + b.x) * w.x;
    acc += lrelu(a.y + b.y) * w.y;
    acc += lrelu(a.z + b.z) * w.z;
    acc += lrelu(a.w + b.w) * w.w;
  }
  *outp = acc;
}

// softmax over incoming edges; writes NORMALIZED alpha back in place
// (each (n,h) thread owns its CSR segment -> no race)
__global__ void softmax1_kernel(const int* __restrict__ row_ptr, int N,
                                float* e_csr, float* e_self) {
  int t = blockIdx.x * blockDim.x + threadIdx.x;
  if (t >= N * 4) return;
  int n = t >> 2, h = t & 3;
  int p0 = row_ptr[n], p1 = row_ptr[n + 1];
  float m = e_self[t];
  for (int p = p0; p < p1; ++p) m = fmaxf(m, e_csr[(size_t)p * 4 + h]);
  float s = __expf(e_self[t] - m);
  for (int p = p0; p < p1; ++p) s += __expf(e_csr[(size_t)p * 4 + h] - m);
  float is = 1.0f / s;
  e_self[t] = __expf(e_self[t] - m) * is;
  for (int p = p0; p < p1; ++p) {
    size_t q = (size_t)p * 4 + h;
    e_csr[q] = __expf(e_csr[q] - m) * is;
  }
}

// aggregation: pure weighted gather, alpha precomputed
__global__ __launch_bounds__(256) void agg1_kernel(
    const int* __restrict__ row_ptr, const int* __restrict__ csr_src, int N,
    const float* __restrict__ xl, const float* __restrict__ alpha_csr,
    const float* __restrict__ alpha_self, const float* __restrict__ bias,
    float* __restrict__ out) {
  int n = blockIdx.x * 4 + (threadIdx.x >> 6);
  if (n >= N) return;
  int c = threadIdx.x & 63, h = c >> 4;
  float acc = alpha_self[n * 4 + h] * xl[(size_t)n * 64 + c];
  int p0 = row_ptr[n], p1 = row_ptr[n + 1];
  for (int p = p0; p < p1; ++p) {
    int s = csr_src[p];
    acc = fmaf(alpha_csr[(size_t)p * 4 + h], xl[(size_t)s * 64 + c], acc);
  }
  float v = acc + bias[c];
  out[(size_t)n * 64 + c] = v > 0.f ? v : expm1f(v);  // fused ELU
}

// ---------------- conv2 edge attention logits (H=1, C=64), 16 lanes/edge ----------------
__global__ void edge_e2_kernel(const int* __restrict__ csr_src, const int* __restrict__ csr_dst,
                               int E, int N,
                               const float* __restrict__ xl, const float* __restrict__ xr,
                               const float* __restrict__ att,
                               float* __restrict__ e_csr, float* __restrict__ e_self) {
  int t = blockIdx.x * blockDim.x + threadIdx.x;
  int pos = t >> 4, l = t & 15;
  if (pos >= E + N) return;
  int s, d;
  if (pos < E) { s = csr_src[pos]; d = csr_dst[pos]; }
  else { s = d = pos - E; }
  float4 a = ld4(xl + (size_t)s * 64 + l * 4);
  float4 b = ld4(xr + (size_t)d * 64 + l * 4);
  float4 w = ld4(att + l * 4);
  float acc = lrelu(a.x + b.x) * w.x + lrelu(a.y + b.y) * w.y +
              lrelu(a.z + b.z) * w.z + lrelu(a.w + b.w) * w.w;
  acc += __shfl_xor(acc, 1);
  acc += __shfl_xor(acc, 2);
  acc += __shfl_xor(acc, 4);
  acc += __shfl_xor(acc, 8);
  if (l == 0) {
    if (pos < E) e_csr[pos] = acc;
    else e_self[pos - E] = acc;
  }
}

__global__ void softmax2_kernel(const int* __restrict__ row_ptr, int N,
                                float* e_csr, float* e_self) {
  int n = blockIdx.x * blockDim.x + threadIdx.x;
  if (n >= N) return;
  int p0 = row_ptr[n], p1 = row_ptr[n + 1];
  float m = e_self[n];
  for (int p = p0; p < p1; ++p) m = fmaxf(m, e_csr[p]);
  float s = __expf(e_self[n] - m);
  for (int p = p0; p < p1; ++p) s += __expf(e_csr[p] - m);
  float is = 1.0f / s;
  e_self[n] = __expf(e_self[n] - m) * is;
  for (int p = p0; p < p1; ++p) e_csr[p] = __expf(e_csr[p] - m) * is;
}

// conv2 aggregation + bias2 + final linear (64->1) fused
__global__ __launch_bounds__(256) void agg2_kernel(
    const int* __restrict__ row_ptr, const int* __restrict__ csr_src, int N,
    const float* __restrict__ xl, const float* __restrict__ alpha_csr,
    const float* __restrict__ alpha_self, const float* __restrict__ bias,
    const float* __restrict__ Wlin, const float* __restrict__ blin,
    float* __restrict__ out) {
  int n = blockIdx.x * 4 + (threadIdx.x >> 6);
  if (n >= N) return;
  int c = threadIdx.x & 63;
  float acc = alpha_self[n] * xl[(size_t)n * 64 + c];
  int p0 = row_ptr[n], p1 = row_ptr[n + 1];
  for (int p = p0; p < p1; ++p) {
    int s = csr_src[p];
    acc = fmaf(alpha_csr[p], xl[(size_t)s * 64 + c], acc);
  }
  float y = (acc + bias[c]) * Wlin[c];
  #pragma unroll
  for (int off = 32; off >= 1; off >>= 1) y += __shfl_down(y, off);
  if (c == 0) out[n] = y + blin[0];
}

// ---------------- launch ----------------
extern "C" void kernel_launch(void* const* d_in, const int* in_sizes, int n_in,
                              void* d_out, int out_size, void* d_ws, size_t ws_size,
                              hipStream_t stream) {
  const float* x     = (const float*)d_in[0];
  const int*   ei    = (const int*)d_in[1];
  const float* W1l   = (const float*)d_in[2];
  const float* b1l   = (const float*)d_in[3];
  const float* W1r   = (const float*)d_in[4];
  const float* b1r   = (const float*)d_in[5];
  const float* att1  = (const float*)d_in[6];
  const float* bias1 = (const float*)d_in[7];
  const float* W2l   = (const float*)d_in[8];
  const float* b2l   = (const float*)d_in[9];
  const float* W2r   = (const float*)d_in[10];
  const float* b2r   = (const float*)d_in[11];
  const float* att2  = (const float*)d_in[12];
  const float* bias2 = (const float*)d_in[13];
  const float* Wlin  = (const float*)d_in[14];
  const float* blin  = (const float*)d_in[15];
  float* out = (float*)d_out;

  const int Fin = 128;
  const int N = in_sizes[0] / Fin;
  const int E = in_sizes[1] / 2;

  char* w = (char*)d_ws;
  auto alloc = [&](size_t bytes) {
    char* p = w;
    w += (bytes + 255) & ~(size_t)255;
    return p;
  };
  float* xl1 = (float*)alloc((size_t)N * 64 * 4);
  float* xr1 = (float*)alloc((size_t)N * 64 * 4);
  float* h1  = (float*)alloc((size_t)N * 64 * 4);
  float* e1  = (float*)alloc((size_t)E * 4 * 4);
  float* es1 = (float*)alloc((size_t)N * 4 * 4);
  int* row_ptr = (int*)alloc((size_t)(N + 1) * 4);
  int* cursor  = (int*)alloc((size_t)N * 4);
  int* csr_src = (int*)alloc((size_t)E * 4);
  int* csr_dst = (int*)alloc((size_t)E * 4);
  // conv2 reuses conv1 buffers (conv1 versions dead by then)
  float* xl2 = xl1; float* xr2 = xr1;
  float* e2 = e1;  float* es2 = es1;

  const int tpb = 256;

  // CSR build
  hipMemsetAsync(cursor, 0, (size_t)N * 4, stream);
  hist_kernel<<<(E + tpb - 1) / tpb, tpb, 0, stream>>>(ei, E, cursor);
  scan_kernel<<<1, 1024, 0, stream>>>(cursor, N, row_ptr, cursor);
  scatter_kernel<<<(E + tpb - 1) / tpb, tpb, 0, stream>>>(ei, E, cursor, csr_src, csr_dst);

  // conv1
  gemm_dual<128><<<(N + 127) / 128, 256, 0, stream>>>(x, N, W1l, b1l, W1r, b1r, xl1, xr1);
  {
    long long T = (long long)(E + N) * 4;
    edge_e1_kernel<<<(int)((T + tpb - 1) / tpb), tpb, 0, stream>>>(csr_src, csr_dst, E, N, xl1, xr1, att1, e1, es1);
  }
  softmax1_kernel<<<((N * 4) + tpb - 1) / tpb, tpb, 0, stream>>>(row_ptr, N, e1, es1);
  agg1_kernel<<<(N + 3) / 4, 256, 0, stream>>>(row_ptr, csr_src, N, xl1, e1, es1, bias1, h1);

  // conv2
  gemm_dual<64><<<(N + 127) / 128, 256, 0, stream>>>(h1, N, W2l, b2l, W2r, b2r, xl2, xr2);
  {
    long long T = (long long)(E + N) * 16;
    edge_e2_kernel<<<(int)((T + tpb - 1) / tpb), tpb, 0, stream>>>(csr_src, csr_dst, E, N, xl2, xr2, att2, e2, es2);
  }
  softmax2_kernel<<<(N + tpb - 1) / tpb, tpb, 0, stream>>>(row_ptr, N, e2, es2);
  agg2_kernel<<<(N + 3) / 4, 256, 0, stream>>>(row_ptr, csr_src, N, xl2, e2, es2, bias2, Wlin, blin, out);
}

// Round 4
// 504.737 us; speedup vs baseline: 1.1141x; 1.1141x over previous
//
#include <hip/hip_runtime.h>
#include <math.h>

#define DEV __device__ __forceinline__

DEV float lrelu(float v) { return v > 0.f ? v : 0.2f * v; }
DEV float4 ld4(const float* p) { return *reinterpret_cast<const float4*>(p); }

// ---------------- CSR build ----------------
__global__ void hist_kernel(const int* __restrict__ ei, int E, int* __restrict__ cnt) {
  int e = blockIdx.x * blockDim.x + threadIdx.x;
  if (e < E) atomicAdd(&cnt[ei[E + e]], 1);
}

// single-block scan (cnt may alias cursor; no __restrict__ here on purpose)
__global__ __launch_bounds__(1024) void scan_kernel(const int* cnt, int N,
                                                    int* row_ptr, int* cursor) {
  __shared__ int wsum[16];
  __shared__ int s_carry;
  const int tid = threadIdx.x;
  const int lane = tid & 63;
  const int wid = tid >> 6;
  if (tid == 0) s_carry = 0;
  __syncthreads();
  for (int base = 0; base < N; base += 1024) {
    int i = base + tid;
    int v = (i < N) ? cnt[i] : 0;
    int x = v;
    #pragma unroll
    for (int off = 1; off < 64; off <<= 1) {
      int y = __shfl_up(x, off);
      if (lane >= off) x += y;
    }
    if (lane == 63) wsum[wid] = x;
    __syncthreads();
    int woff = 0;
    for (int ww = 0; ww < wid; ++ww) woff += wsum[ww];
    int carry = s_carry;
    int incl = carry + woff + x;
    if (i < N) { row_ptr[i] = incl - v; cursor[i] = incl - v; }
    __syncthreads();
    if (tid == 1023) s_carry = incl;
    __syncthreads();
  }
  if (tid == 0) row_ptr[N] = s_carry;
}

__global__ void scatter_kernel(const int* __restrict__ ei, int E,
                               int* __restrict__ cursor,
                               int* __restrict__ csr_src, int* __restrict__ csr_dst) {
  int e = blockIdx.x * blockDim.x + threadIdx.x;
  if (e >= E) return;
  int s = ei[e], d = ei[E + e];
  int pos = atomicAdd(&cursor[d], 1);
  csr_src[pos] = s;
  csr_dst[pos] = d;
}

// ---------------- fused dual GEMM: Xl = A*Wl+bl, Xr = A*Wr+br ----------------
template <int K>
__global__ __launch_bounds__(256) void gemm_dual(
    const float* __restrict__ A, int N,
    const float* __restrict__ Wl, const float* __restrict__ bl,
    const float* __restrict__ Wr, const float* __restrict__ br,
    float* __restrict__ Xl, float* __restrict__ Xr) {
  constexpr int KC = 32;
  constexpr int BR = 128;
  constexpr int LDA = BR + 4;
  constexpr int LDW = 128 + 4;
  __shared__ float sA[KC][LDA];
  __shared__ float sW[KC][LDW];
  const int tid = threadIdx.x;
  const int rb = blockIdx.x * BR;
  const int rowg = tid >> 4;
  const int colg = tid & 15;
  float acc[8][8];
  #pragma unroll
  for (int i = 0; i < 8; ++i)
    #pragma unroll
    for (int j = 0; j < 8; ++j) acc[i][j] = 0.f;

  for (int kc = 0; kc < K; kc += KC) {
    #pragma unroll
    for (int rep = 0; rep < 4; ++rep) {
      int lin = rep * 1024 + tid * 4;
      int k = lin >> 7, j = lin & 127;
      const float* src = (j < 64) ? (Wl + (size_t)(kc + k) * 64 + j)
                                  : (Wr + (size_t)(kc + k) * 64 + (j - 64));
      *reinterpret_cast<float4*>(&sW[k][j]) = ld4(src);
    }
    #pragma unroll
    for (int rep = 0; rep < 4; ++rep) {
      int lin = rep * 1024 + tid * 4;
      int r = lin >> 5;
      int kk = lin & 31;
      int row = rb + r;
      if (row >= N) row = N - 1;
      float4 v = ld4(A + (size_t)row * K + kc + kk);
      sA[kk + 0][r] = v.x;
      sA[kk + 1][r] = v.y;
      sA[kk + 2][r] = v.z;
      sA[kk + 3][r] = v.w;
    }
    __syncthreads();
    #pragma unroll
    for (int k = 0; k < KC; ++k) {
      float a[8], wv[8];
      *reinterpret_cast<float4*>(&a[0]) = *reinterpret_cast<const float4*>(&sA[k][rowg * 8]);
      *reinterpret_cast<float4*>(&a[4]) = *reinterpret_cast<const float4*>(&sA[k][rowg * 8 + 4]);
      *reinterpret_cast<float4*>(&wv[0]) = *reinterpret_cast<const float4*>(&sW[k][colg * 8]);
      *reinterpret_cast<float4*>(&wv[4]) = *reinterpret_cast<const float4*>(&sW[k][colg * 8 + 4]);
      #pragma unroll
      for (int i = 0; i < 8; ++i)
        #pragma unroll
        for (int j = 0; j < 8; ++j) acc[i][j] = fmaf(a[i], wv[j], acc[i][j]);
    }
    __syncthreads();
  }
  const int cb = colg * 8;
  float bv[8];
  #pragma unroll
  for (int j = 0; j < 8; ++j) bv[j] = (cb < 64) ? bl[cb + j] : br[cb - 64 + j];
  #pragma unroll
  for (int i = 0; i < 8; ++i) {
    int row = rb + rowg * 8 + i;
    if (row < N) {
      float o[8];
      #pragma unroll
      for (int j = 0; j < 8; ++j) o[j] = acc[i][j] + bv[j];
      float* dst = (cb < 64) ? (Xl + (size_t)row * 64 + cb) : (Xr + (size_t)row * 64 + cb - 64);
      *reinterpret_cast<float4*>(dst) = make_float4(o[0], o[1], o[2], o[3]);
      *reinterpret_cast<float4*>(dst + 4) = make_float4(o[4], o[5], o[6], o[7]);
    }
  }
}

// ---------------- conv1 edge attention logits (H=4, C=16) ----------------
__global__ void edge_e1_kernel(const int* __restrict__ csr_src, const int* __restrict__ csr_dst,
                               int E, int N,
                               const float* __restrict__ xl, const float* __restrict__ xr,
                               const float* __restrict__ att,
                               float* __restrict__ e_csr, float* __restrict__ e_self) {
  int t = blockIdx.x * blockDim.x + threadIdx.x;
  int pos = t >> 2, h = t & 3;
  if (pos >= E + N) return;
  int s, d;
  float* outp;
  if (pos < E) {
    s = csr_src[pos]; d = csr_dst[pos];
    outp = e_csr + (size_t)pos * 4 + h;
  } else {
    int n = pos - E; s = n; d = n;
    outp = e_self + (size_t)n * 4 + h;
  }
  const float* pa = xl + (size_t)s * 64 + h * 16;
  const float* pb = xr + (size_t)d * 64 + h * 16;
  const float* pw = att + h * 16;
  float acc = 0.f;
  #pragma unroll
  for (int q = 0; q < 4; ++q) {
    float4 a = ld4(pa + q * 4), b = ld4(pb + q * 4), w = ld4(pw + q * 4);
    acc += lrelu(a.x + b.x) * w.x;
    acc += lrelu(a.y + b.y) * w.y;
    acc += lrelu(a.z + b.z) * w.z;
    acc += lrelu(a.w + b.w) * w.w;
  }
  *outp = acc;
}

// ---------------- softmax conv1: wave-per-node, coalesced, in-register ----------------
// lane l: head h = l>>4, edge-slot e = l&15. Writes normalized alpha in place.
__global__ __launch_bounds__(256) void softmax1_kernel(const int* __restrict__ row_ptr, int N,
                                                       float* e_csr, float* e_self) {
  int n = blockIdx.x * 4 + (threadIdx.x >> 6);
  if (n >= N) return;
  const int l = threadIdx.x & 63;
  const int h = l >> 4, e = l & 15;
  const int p0 = row_ptr[n], p1 = row_ptr[n + 1];
  const float es = e_self[n * 4 + h];

  const float NINF = -INFINITY;
  float ev0 = NINF, ev1 = NINF, ev2 = NINF, ev3 = NINF;
  int i0 = p0 + e, i1 = p0 + 16 + e, i2 = p0 + 32 + e, i3 = p0 + 48 + e;
  if (i0 < p1) ev0 = e_csr[(size_t)i0 * 4 + h];
  if (i1 < p1) ev1 = e_csr[(size_t)i1 * 4 + h];
  if (i2 < p1) ev2 = e_csr[(size_t)i2 * 4 + h];
  if (i3 < p1) ev3 = e_csr[(size_t)i3 * 4 + h];

  float m = fmaxf(es, fmaxf(fmaxf(ev0, ev1), fmaxf(ev2, ev3)));
  for (int q = p0 + 64 + e; q < p1; q += 16) m = fmaxf(m, e_csr[(size_t)q * 4 + h]);
  #pragma unroll
  for (int off = 1; off < 16; off <<= 1) m = fmaxf(m, __shfl_xor(m, off));

  float x0 = __expf(ev0 - m), x1 = __expf(ev1 - m);
  float x2 = __expf(ev2 - m), x3 = __expf(ev3 - m);
  float part = x0 + x1 + x2 + x3;
  for (int q = p0 + 64 + e; q < p1; q += 16) part += __expf(e_csr[(size_t)q * 4 + h] - m);
  #pragma unroll
  for (int off = 1; off < 16; off <<= 1) part += __shfl_xor(part, off);
  float is = 1.0f / (part + __expf(es - m));

  if (i0 < p1) e_csr[(size_t)i0 * 4 + h] = x0 * is;
  if (i1 < p1) e_csr[(size_t)i1 * 4 + h] = x1 * is;
  if (i2 < p1) e_csr[(size_t)i2 * 4 + h] = x2 * is;
  if (i3 < p1) e_csr[(size_t)i3 * 4 + h] = x3 * is;
  for (int q = p0 + 64 + e; q < p1; q += 16)
    e_csr[(size_t)q * 4 + h] = __expf(e_csr[(size_t)q * 4 + h] - m) * is;
  if (e == 0) e_self[n * 4 + h] = __expf(es - m) * is;
}

// ---------------- conv1 aggregation: batched gather with shuffle broadcast ----------------
__global__ __launch_bounds__(256) void agg1_kernel(
    const int* __restrict__ row_ptr, const int* __restrict__ csr_src, int N,
    const float* __restrict__ xl, const float* __restrict__ alpha_csr,
    const float* __restrict__ alpha_self, const float* __restrict__ bias,
    float* __restrict__ out) {
  int n = blockIdx.x * 4 + (threadIdx.x >> 6);
  if (n >= N) return;
  const int c = threadIdx.x & 63;
  const int hq = c >> 4;  // head of this lane
  float acc = alpha_self[n * 4 + hq] * xl[(size_t)n * 64 + c];
  const int p0 = row_ptr[n], p1 = row_ptr[n + 1];
  int p = p0;
  // full batches of 16 edges: one coalesced idx load + one coalesced alpha load,
  // then 16 independent gathers (register-broadcast addresses)
  for (; p + 16 <= p1; p += 16) {
    int sv = csr_src[p + (c & 15)];
    float av = alpha_csr[(size_t)p * 4 + c];  // lane l holds alpha[edge l>>2][head l&3]
    #pragma unroll
    for (int j = 0; j < 16; ++j) {
      int s = __shfl(sv, j);
      float a = __shfl(av, (j << 2) | hq);
      acc = fmaf(a, xl[(size_t)s * 64 + c], acc);
    }
  }
  if (p < p1) {
    int nb = p1 - p;
    int lidx = p + (c & 15); if (lidx >= p1) lidx = p1 - 1;
    int sv = csr_src[lidx];
    float av = alpha_csr[(size_t)p * 4 + c];  // alpha buffer padded by 64 floats
    #pragma unroll 4
    for (int j = 0; j < nb; ++j) {
      int s = __shfl(sv, j);
      float a = __shfl(av, (j << 2) | hq);
      acc = fmaf(a, xl[(size_t)s * 64 + c], acc);
    }
  }
  float v = acc + bias[c];
  out[(size_t)n * 64 + c] = v > 0.f ? v : expm1f(v);  // fused ELU
}

// ---------------- conv2 edge attention logits (H=1, C=64), 16 lanes/edge ----------------
__global__ void edge_e2_kernel(const int* __restrict__ csr_src, const int* __restrict__ csr_dst,
                               int E, int N,
                               const float* __restrict__ xl, const float* __restrict__ xr,
                               const float* __restrict__ att,
                               float* __restrict__ e_csr, float* __restrict__ e_self) {
  int t = blockIdx.x * blockDim.x + threadIdx.x;
  int pos = t >> 4, l = t & 15;
  if (pos >= E + N) return;
  int s, d;
  if (pos < E) { s = csr_src[pos]; d = csr_dst[pos]; }
  else { s = d = pos - E; }
  float4 a = ld4(xl + (size_t)s * 64 + l * 4);
  float4 b = ld4(xr + (size_t)d * 64 + l * 4);
  float4 w = ld4(att + l * 4);
  float acc = lrelu(a.x + b.x) * w.x + lrelu(a.y + b.y) * w.y +
              lrelu(a.z + b.z) * w.z + lrelu(a.w + b.w) * w.w;
  acc += __shfl_xor(acc, 1);
  acc += __shfl_xor(acc, 2);
  acc += __shfl_xor(acc, 4);
  acc += __shfl_xor(acc, 8);
  if (l == 0) {
    if (pos < E) e_csr[pos] = acc;
    else e_self[pos - E] = acc;
  }
}

// ---------------- softmax conv2: wave-per-node, coalesced, in-register ----------------
__global__ __launch_bounds__(256) void softmax2_kernel(const int* __restrict__ row_ptr, int N,
                                                       float* e_csr, float* e_self) {
  int n = blockIdx.x * 4 + (threadIdx.x >> 6);
  if (n >= N) return;
  const int l = threadIdx.x & 63;
  const int p0 = row_ptr[n], p1 = row_ptr[n + 1];
  const float es = e_self[n];

  const float NINF = -INFINITY;
  float ev0 = NINF, ev1 = NINF;
  int i0 = p0 + l, i1 = p0 + 64 + l;
  if (i0 < p1) ev0 = e_csr[i0];
  if (i1 < p1) ev1 = e_csr[i1];
  float m = fmaxf(es, fmaxf(ev0, ev1));
  for (int q = p0 + 128 + l; q < p1; q += 64) m = fmaxf(m, e_csr[q]);
  #pragma unroll
  for (int off = 1; off < 64; off <<= 1) m = fmaxf(m, __shfl_xor(m, off));

  float x0 = __expf(ev0 - m), x1 = __expf(ev1 - m);
  float part = x0 + x1;
  for (int q = p0 + 128 + l; q < p1; q += 64) part += __expf(e_csr[q] - m);
  #pragma unroll
  for (int off = 1; off < 64; off <<= 1) part += __shfl_xor(part, off);
  float is = 1.0f / (part + __expf(es - m));

  if (i0 < p1) e_csr[i0] = x0 * is;
  if (i1 < p1) e_csr[i1] = x1 * is;
  for (int q = p0 + 128 + l; q < p1; q += 64) e_csr[q] = __expf(e_csr[q] - m) * is;
  if (l == 0) e_self[n] = __expf(es - m) * is;
}

// ---------------- conv2 aggregation + bias2 + final linear (64->1) fused ----------------
__global__ __launch_bounds__(256) void agg2_kernel(
    const int* __restrict__ row_ptr, const int* __restrict__ csr_src, int N,
    const float* __restrict__ xl, const float* __restrict__ alpha_csr,
    const float* __restrict__ alpha_self, const float* __restrict__ bias,
    const float* __restrict__ Wlin, const float* __restrict__ blin,
    float* __restrict__ out) {
  int n = blockIdx.x * 4 + (threadIdx.x >> 6);
  if (n >= N) return;
  const int c = threadIdx.x & 63;
  float acc = alpha_self[n] * xl[(size_t)n * 64 + c];
  const int p0 = row_ptr[n], p1 = row_ptr[n + 1];
  int p = p0;
  for (; p + 16 <= p1; p += 16) {
    int sv = csr_src[p + (c & 15)];
    float av = alpha_csr[p + (c & 15)];
    #pragma unroll
    for (int j = 0; j < 16; ++j) {
      int s = __shfl(sv, j);
      float a = __shfl(av, j);
      acc = fmaf(a, xl[(size_t)s * 64 + c], acc);
    }
  }
  if (p < p1) {
    int nb = p1 - p;
    int lidx = p + (c & 15); if (lidx >= p1) lidx = p1 - 1;
    int sv = csr_src[lidx];
    float av = alpha_csr[lidx];
    #pragma unroll 4
    for (int j = 0; j < nb; ++j) {
      int s = __shfl(sv, j);
      float a = __shfl(av, j);
      acc = fmaf(a, xl[(size_t)s * 64 + c], acc);
    }
  }
  float y = (acc + bias[c]) * Wlin[c];
  #pragma unroll
  for (int off = 32; off >= 1; off >>= 1) y += __shfl_down(y, off);
  if (c == 0) out[n] = y + blin[0];
}

// ---------------- launch ----------------
extern "C" void kernel_launch(void* const* d_in, const int* in_sizes, int n_in,
                              void* d_out, int out_size, void* d_ws, size_t ws_size,
                              hipStream_t stream) {
  const float* x     = (const float*)d_in[0];
  const int*   ei    = (const int*)d_in[1];
  const float* W1l   = (const float*)d_in[2];
  const float* b1l   = (const float*)d_in[3];
  const float* W1r   = (const float*)d_in[4];
  const float* b1r   = (const float*)d_in[5];
  const float* att1  = (const float*)d_in[6];
  const float* bias1 = (const float*)d_in[7];
  const float* W2l   = (const float*)d_in[8];
  const float* b2l   = (const float*)d_in[9];
  const float* W2r   = (const float*)d_in[10];
  const float* b2r   = (const float*)d_in[11];
  const float* att2  = (const float*)d_in[12];
  const float* bias2 = (const float*)d_in[13];
  const float* Wlin  = (const float*)d_in[14];
  const float* blin  = (const float*)d_in[15];
  float* out = (float*)d_out;

  const int Fin = 128;
  const int N = in_sizes[0] / Fin;
  const int E = in_sizes[1] / 2;

  char* w = (char*)d_ws;
  auto alloc = [&](size_t bytes) {
    char* p = w;
    w += (bytes + 255) & ~(size_t)255;
    return p;
  };
  float* xl1 = (float*)alloc((size_t)N * 64 * 4);
  float* xr1 = (float*)alloc((size_t)N * 64 * 4);
  float* h1  = (float*)alloc((size_t)N * 64 * 4);
  float* e1  = (float*)alloc(((size_t)E * 4 + 64) * 4);  // +64 floats pad for batch tail
  float* es1 = (float*)alloc((size_t)N * 4 * 4);
  int* row_ptr = (int*)alloc((size_t)(N + 1) * 4);
  int* cursor  = (int*)alloc((size_t)N * 4);
  int* csr_src = (int*)alloc((size_t)E * 4);
  int* csr_dst = (int*)alloc((size_t)E * 4);
  // conv2 reuses conv1 buffers (conv1 versions dead by then)
  float* xl2 = xl1; float* xr2 = xr1;
  float* e2 = e1;  float* es2 = es1;

  const int tpb = 256;

  // CSR build
  hipMemsetAsync(cursor, 0, (size_t)N * 4, stream);
  hist_kernel<<<(E + tpb - 1) / tpb, tpb, 0, stream>>>(ei, E, cursor);
  scan_kernel<<<1, 1024, 0, stream>>>(cursor, N, row_ptr, cursor);
  scatter_kernel<<<(E + tpb - 1) / tpb, tpb, 0, stream>>>(ei, E, cursor, csr_src, csr_dst);

  // conv1
  gemm_dual<128><<<(N + 127) / 128, 256, 0, stream>>>(x, N, W1l, b1l, W1r, b1r, xl1, xr1);
  {
    long long T = (long long)(E + N) * 4;
    edge_e1_kernel<<<(int)((T + tpb - 1) / tpb), tpb, 0, stream>>>(csr_src, csr_dst, E, N, xl1, xr1, att1, e1, es1);
  }
  softmax1_kernel<<<(N + 3) / 4, 256, 0, stream>>>(row_ptr, N, e1, es1);
  agg1_kernel<<<(N + 3) / 4, 256, 0, stream>>>(row_ptr, csr_src, N, xl1, e1, es1, bias1, h1);

  // conv2
  gemm_dual<64><<<(N + 127) / 128, 256, 0, stream>>>(h1, N, W2l, b2l, W2r, b2r, xl2, xr2);
  {
    long long T = (long long)(E + N) * 16;
    edge_e2_kernel<<<(int)((T + tpb - 1) / tpb), tpb, 0, stream>>>(csr_src, csr_dst, E, N, xl2, xr2, att2, e2, es2);
  }
  softmax2_kernel<<<(N + 3) / 4, 256, 0, stream>>>(row_ptr, N, e2, es2);
  agg2_kernel<<<(N + 3) / 4, 256, 0, stream>>>(row_ptr, csr_src, N, xl2, e2, es2, bias2, Wlin, blin, out);
}

// Round 10
// 407.241 us; speedup vs baseline: 1.3809x; 1.2394x over previous
//
#include <hip/hip_runtime.h>
#include <math.h>

#define DEV __device__ __forceinline__

DEV float lrelu(float v) { return v > 0.f ? v : 0.2f * v; }
DEV float4 ld4(const float* p) { return *reinterpret_cast<const float4*>(p); }

// ---------------- CSR build ----------------
__global__ void hist_kernel(const int* __restrict__ ei, int E, int* __restrict__ cnt) {
  int e = blockIdx.x * blockDim.x + threadIdx.x;
  if (e < E) atomicAdd(&cnt[ei[E + e]], 1);
}

// block-level partial sums (tile = 1024)
__global__ __launch_bounds__(1024) void partial_kernel(const int* __restrict__ cnt, int N,
                                                       int* __restrict__ partials) {
  __shared__ int ws[16];
  int i = blockIdx.x * 1024 + threadIdx.x;
  int v = (i < N) ? cnt[i] : 0;
  #pragma unroll
  for (int off = 32; off >= 1; off >>= 1) v += __shfl_down(v, off);
  int lane = threadIdx.x & 63, wid = threadIdx.x >> 6;
  if (lane == 0) ws[wid] = v;
  __syncthreads();
  if (threadIdx.x < 64) {  // whole first wave active -> shfl defined
    int t = (threadIdx.x < 16) ? ws[threadIdx.x] : 0;
    #pragma unroll
    for (int off = 8; off >= 1; off >>= 1) t += __shfl_down(t, off);
    if (threadIdx.x == 0) partials[blockIdx.x] = t;
  }
}

// per-block: offset = sum of preceding partials (small scalar loop), intra-block scan.
// cnt aliases cursor (each thread reads then writes only its own index) -> no __restrict__.
__global__ __launch_bounds__(1024) void apply_kernel(const int* cnt,
                                                     const int* __restrict__ partials,
                                                     int N, int* __restrict__ row_ptr,
                                                     int* cursor) {
  __shared__ int wsum[16];
  int off = 0;
  for (int i = 0; i < (int)blockIdx.x; ++i) off += partials[i];
  const int tid = threadIdx.x, lane = tid & 63, wid = tid >> 6;
  int i = blockIdx.x * 1024 + tid;
  int v = (i < N) ? cnt[i] : 0;
  int x = v;
  #pragma unroll
  for (int o = 1; o < 64; o <<= 1) {
    int y = __shfl_up(x, o);
    if (lane >= o) x += y;
  }
  if (lane == 63) wsum[wid] = x;
  __syncthreads();
  int woff = 0;
  for (int ww = 0; ww < wid; ++ww) woff += wsum[ww];
  int excl = off + woff + x - v;
  if (i < N) { row_ptr[i] = excl; cursor[i] = excl; }
  if (i == N - 1) row_ptr[N] = excl + v;
}

__global__ void scatter_kernel(const int* __restrict__ ei, int E,
                               int* __restrict__ cursor, int* __restrict__ csr_src) {
  int e = blockIdx.x * blockDim.x + threadIdx.x;
  if (e >= E) return;
  int s = ei[e], d = ei[E + e];
  int pos = atomicAdd(&cursor[d], 1);
  csr_src[pos] = s;
}

// ---------------- fused dual GEMM: Xl = A*Wl+bl, Xr = A*Wr+br ----------------
template <int K>
__global__ __launch_bounds__(256) void gemm_dual(
    const float* __restrict__ A, int N,
    const float* __restrict__ Wl, const float* __restrict__ bl,
    const float* __restrict__ Wr, const float* __restrict__ br,
    float* __restrict__ Xl, float* __restrict__ Xr) {
  constexpr int KC = 32;
  constexpr int BR = 128;
  constexpr int LDA = BR + 4;
  constexpr int LDW = 128 + 4;
  __shared__ float sA[KC][LDA];
  __shared__ float sW[KC][LDW];
  const int tid = threadIdx.x;
  const int rb = blockIdx.x * BR;
  const int rowg = tid >> 4;
  const int colg = tid & 15;
  float acc[8][8];
  #pragma unroll
  for (int i = 0; i < 8; ++i)
    #pragma unroll
    for (int j = 0; j < 8; ++j) acc[i][j] = 0.f;

  for (int kc = 0; kc < K; kc += KC) {
    #pragma unroll
    for (int rep = 0; rep < 4; ++rep) {
      int lin = rep * 1024 + tid * 4;
      int k = lin >> 7, j = lin & 127;
      const float* src = (j < 64) ? (Wl + (size_t)(kc + k) * 64 + j)
                                  : (Wr + (size_t)(kc + k) * 64 + (j - 64));
      *reinterpret_cast<float4*>(&sW[k][j]) = ld4(src);
    }
    #pragma unroll
    for (int rep = 0; rep < 4; ++rep) {
      int lin = rep * 1024 + tid * 4;
      int r = lin >> 5;
      int kk = lin & 31;
      int row = rb + r;
      if (row >= N) row = N - 1;
      float4 v = ld4(A + (size_t)row * K + kc + kk);
      sA[kk + 0][r] = v.x;
      sA[kk + 1][r] = v.y;
      sA[kk + 2][r] = v.z;
      sA[kk + 3][r] = v.w;
    }
    __syncthreads();
    #pragma unroll
    for (int k = 0; k < KC; ++k) {
      float a[8], wv[8];
      *reinterpret_cast<float4*>(&a[0]) = *reinterpret_cast<const float4*>(&sA[k][rowg * 8]);
      *reinterpret_cast<float4*>(&a[4]) = *reinterpret_cast<const float4*>(&sA[k][rowg * 8 + 4]);
      *reinterpret_cast<float4*>(&wv[0]) = *reinterpret_cast<const float4*>(&sW[k][colg * 8]);
      *reinterpret_cast<float4*>(&wv[4]) = *reinterpret_cast<const float4*>(&sW[k][colg * 8 + 4]);
      #pragma unroll
      for (int i = 0; i < 8; ++i)
        #pragma unroll
        for (int j = 0; j < 8; ++j) acc[i][j] = fmaf(a[i], wv[j], acc[i][j]);
    }
    __syncthreads();
  }
  const int cb = colg * 8;
  float bv[8];
  #pragma unroll
  for (int j = 0; j < 8; ++j) bv[j] = (cb < 64) ? bl[cb + j] : br[cb - 64 + j];
  #pragma unroll
  for (int i = 0; i < 8; ++i) {
    int row = rb + rowg * 8 + i;
    if (row < N) {
      float o[8];
      #pragma unroll
      for (int j = 0; j < 8; ++j) o[j] = acc[i][j] + bv[j];
      float* dst = (cb < 64) ? (Xl + (size_t)row * 64 + cb) : (Xr + (size_t)row * 64 + cb - 64);
      *reinterpret_cast<float4*>(dst) = make_float4(o[0], o[1], o[2], o[3]);
      *reinterpret_cast<float4*>(dst + 4) = make_float4(o[4], o[5], o[6], o[7]);
    }
  }
}

// ---------------- conv1 fused: edge logits + online softmax + aggregation ----------------
// wave-per-node; lane c = channel, head h = c>>4. Single gather of xl[s] per edge.
__global__ __launch_bounds__(256) void fused1_kernel(
    const int* __restrict__ row_ptr, const int* __restrict__ csr_src, int N,
    const float* __restrict__ xl, const float* __restrict__ xr,
    const float* __restrict__ att, const float* __restrict__ bias,
    float* __restrict__ out) {
  int n = blockIdx.x * 4 + (threadIdx.x >> 6);
  if (n >= N) return;
  const int c = threadIdx.x & 63;
  const float attc = att[c];                      // att[h][c&15] flat
  const float xrc = xr[(size_t)n * 64 + c];
  const float xls = xl[(size_t)n * 64 + c];
  // self edge initializes the online softmax state
  float t = lrelu(xls + xrc) * attc;
  t += __shfl_xor(t, 1); t += __shfl_xor(t, 2);
  t += __shfl_xor(t, 4); t += __shfl_xor(t, 8);
  float m = t;       // running max (per head, uniform within 16-lane group)
  float s = 1.f;     // running sum
  float acc = xls;   // running weighted message (per channel)

  const int p0 = row_ptr[n], p1 = row_ptr[n + 1];
  int p = p0;
  for (; p + 16 <= p1; p += 16) {   // full batches, no guards
    int sv = csr_src[p + (c & 15)];
    float xv[16];
    #pragma unroll
    for (int j = 0; j < 16; ++j) {
      int sj = __shfl(sv, j);
      xv[j] = xl[(size_t)sj * 64 + c];
    }
    float ev[16];
    #pragma unroll
    for (int j = 0; j < 16; ++j) {
      float u = lrelu(xv[j] + xrc) * attc;
      u += __shfl_xor(u, 1); u += __shfl_xor(u, 2);
      u += __shfl_xor(u, 4); u += __shfl_xor(u, 8);
      ev[j] = u;
    }
    float bm = ev[0];
    #pragma unroll
    for (int j = 1; j < 16; ++j) bm = fmaxf(bm, ev[j]);
    float mn = fmaxf(m, bm);
    float sc = __expf(m - mn);
    s *= sc; acc *= sc; m = mn;
    #pragma unroll
    for (int j = 0; j < 16; ++j) {
      float pj = __expf(ev[j] - m);
      s += pj;
      acc = fmaf(pj, xv[j], acc);
    }
  }
  if (p < p1) {                     // tail (1..15 edges), wave-uniform lim
    const int lim = p1 - p;
    int lidx = p + (c & 15); if (lidx >= p1) lidx = p1 - 1;
    int sv = csr_src[lidx];
    float xv[16], ev[16];
    #pragma unroll
    for (int j = 0; j < 16; ++j) {
      int sj = __shfl(sv, j);
      xv[j] = xl[(size_t)sj * 64 + c];  // clamped duplicates: safe
    }
    #pragma unroll
    for (int j = 0; j < 16; ++j) {
      float u = lrelu(xv[j] + xrc) * attc;
      u += __shfl_xor(u, 1); u += __shfl_xor(u, 2);
      u += __shfl_xor(u, 4); u += __shfl_xor(u, 8);
      ev[j] = u;
    }
    float bm = ev[0];
    #pragma unroll
    for (int j = 1; j < 16; ++j) if (j < lim) bm = fmaxf(bm, ev[j]);
    float mn = fmaxf(m, bm);
    float sc = __expf(m - mn);
    s *= sc; acc *= sc; m = mn;
    #pragma unroll
    for (int j = 0; j < 16; ++j) if (j < lim) {
      float pj = __expf(ev[j] - m);
      s += pj;
      acc = fmaf(pj, xv[j], acc);
    }
  }
  float v = acc / s + bias[c];
  out[(size_t)n * 64 + c] = v > 0.f ? v : expm1f(v);  // fused ELU
}

// ---------------- conv2 fused (H=1) + bias2 + final linear 64->1 ----------------
__global__ __launch_bounds__(256) void fused2_kernel(
    const int* __restrict__ row_ptr, const int* __restrict__ csr_src, int N,
    const float* __restrict__ xl, const float* __restrict__ xr,
    const float* __restrict__ att, const float* __restrict__ bias,
    const float* __restrict__ Wlin, const float* __restrict__ blin,
    float* __restrict__ out) {
  int n = blockIdx.x * 4 + (threadIdx.x >> 6);
  if (n >= N) return;
  const int c = threadIdx.x & 63;
  const float attc = att[c];
  const float xrc = xr[(size_t)n * 64 + c];
  const float xls = xl[(size_t)n * 64 + c];
  float t = lrelu(xls + xrc) * attc;
  t += __shfl_xor(t, 1); t += __shfl_xor(t, 2); t += __shfl_xor(t, 4);
  t += __shfl_xor(t, 8); t += __shfl_xor(t, 16); t += __shfl_xor(t, 32);
  float m = t;
  float s = 1.f;
  float acc = xls;

  const int p0 = row_ptr[n], p1 = row_ptr[n + 1];
  int p = p0;
  for (; p + 16 <= p1; p += 16) {
    int sv = csr_src[p + (c & 15)];
    float xv[16];
    #pragma unroll
    for (int j = 0; j < 16; ++j) {
      int sj = __shfl(sv, j);
      xv[j] = xl[(size_t)sj * 64 + c];
    }
    float ev[16];
    #pragma unroll
    for (int j = 0; j < 16; ++j) {
      float u = lrelu(xv[j] + xrc) * attc;
      u += __shfl_xor(u, 1); u += __shfl_xor(u, 2); u += __shfl_xor(u, 4);
      u += __shfl_xor(u, 8); u += __shfl_xor(u, 16); u += __shfl_xor(u, 32);
      ev[j] = u;
    }
    float bm = ev[0];
    #pragma unroll
    for (int j = 1; j < 16; ++j) bm = fmaxf(bm, ev[j]);
    float mn = fmaxf(m, bm);
    float sc = __expf(m - mn);
    s *= sc; acc *= sc; m = mn;
    #pragma unroll
    for (int j = 0; j < 16; ++j) {
      float pj = __expf(ev[j] - m);
      s += pj;
      acc = fmaf(pj, xv[j], acc);
    }
  }
  if (p < p1) {
    const int lim = p1 - p;
    int lidx = p + (c & 15); if (lidx >= p1) lidx = p1 - 1;
    int sv = csr_src[lidx];
    float xv[16], ev[16];
    #pragma unroll
    for (int j = 0; j < 16; ++j) {
      int sj = __shfl(sv, j);
      xv[j] = xl[(size_t)sj * 64 + c];
    }
    #pragma unroll
    for (int j = 0; j < 16; ++j) {
      float u = lrelu(xv[j] + xrc) * attc;
      u += __shfl_xor(u, 1); u += __shfl_xor(u, 2); u += __shfl_xor(u, 4);
      u += __shfl_xor(u, 8); u += __shfl_xor(u, 16); u += __shfl_xor(u, 32);
      ev[j] = u;
    }
    float bm = ev[0];
    #pragma unroll
    for (int j = 1; j < 16; ++j) if (j < lim) bm = fmaxf(bm, ev[j]);
    float mn = fmaxf(m, bm);
    float sc = __expf(m - mn);
    s *= sc; acc *= sc; m = mn;
    #pragma unroll
    for (int j = 0; j < 16; ++j) if (j < lim) {
      float pj = __expf(ev[j] - m);
      s += pj;
      acc = fmaf(pj, xv[j], acc);
    }
  }
  float y = (acc / s + bias[c]) * Wlin[c];
  y += __shfl_xor(y, 1); y += __shfl_xor(y, 2); y += __shfl_xor(y, 4);
  y += __shfl_xor(y, 8); y += __shfl_xor(y, 16); y += __shfl_xor(y, 32);
  if (c == 0) out[n] = y + blin[0];
}

// ---------------- launch ----------------
extern "C" void kernel_launch(void* const* d_in, const int* in_sizes, int n_in,
                              void* d_out, int out_size, void* d_ws, size_t ws_size,
                              hipStream_t stream) {
  const float* x     = (const float*)d_in[0];
  const int*   ei    = (const int*)d_in[1];
  const float* W1l   = (const float*)d_in[2];
  const float* b1l   = (const float*)d_in[3];
  const float* W1r   = (const float*)d_in[4];
  const float* b1r   = (const float*)d_in[5];
  const float* att1  = (const float*)d_in[6];
  const float* bias1 = (const float*)d_in[7];
  const float* W2l   = (const float*)d_in[8];
  const float* b2l   = (const float*)d_in[9];
  const float* W2r   = (const float*)d_in[10];
  const float* b2r   = (const float*)d_in[11];
  const float* att2  = (const float*)d_in[12];
  const float* bias2 = (const float*)d_in[13];
  const float* Wlin  = (const float*)d_in[14];
  const float* blin  = (const float*)d_in[15];
  float* out = (float*)d_out;

  const int Fin = 128;
  const int N = in_sizes[0] / Fin;
  const int E = in_sizes[1] / 2;

  char* w = (char*)d_ws;
  auto alloc = [&](size_t bytes) {
    char* p = w;
    w += (bytes + 255) & ~(size_t)255;
    return p;
  };
  float* xl1 = (float*)alloc((size_t)N * 64 * 4);
  float* xr1 = (float*)alloc((size_t)N * 64 * 4);
  float* h1  = (float*)alloc((size_t)N * 64 * 4);
  int* row_ptr  = (int*)alloc((size_t)(N + 1) * 4);
  int* cursor   = (int*)alloc((size_t)N * 4);
  int* partials = (int*)alloc((size_t)256 * 4);
  int* csr_src  = (int*)alloc((size_t)E * 4);
  // conv2 reuses conv1 buffers
  float* xl2 = xl1; float* xr2 = xr1;

  const int tpb = 256;
  const int nscan = (N + 1023) / 1024;

  // CSR build (reduce-then-scan, no serial single-block pass)
  hipMemsetAsync(cursor, 0, (size_t)N * 4, stream);
  hist_kernel<<<(E + tpb - 1) / tpb, tpb, 0, stream>>>(ei, E, cursor);
  partial_kernel<<<nscan, 1024, 0, stream>>>(cursor, N, partials);
  apply_kernel<<<nscan, 1024, 0, stream>>>(cursor, partials, N, row_ptr, cursor);
  scatter_kernel<<<(E + tpb - 1) / tpb, tpb, 0, stream>>>(ei, E, cursor, csr_src);

  // conv1: dual GEMM + fully fused edge/softmax/aggregate (+ELU)
  gemm_dual<128><<<(N + 127) / 128, 256, 0, stream>>>(x, N, W1l, b1l, W1r, b1r, xl1, xr1);
  fused1_kernel<<<(N + 3) / 4, 256, 0, stream>>>(row_ptr, csr_src, N, xl1, xr1, att1, bias1, h1);

  // conv2: dual GEMM + fused (+final linear)
  gemm_dual<64><<<(N + 127) / 128, 256, 0, stream>>>(h1, N, W2l, b2l, W2r, b2r, xl2, xr2);
  fused2_kernel<<<(N + 3) / 4, 256, 0, stream>>>(row_ptr, csr_src, N, xl2, xr2, att2, bias2, Wlin, blin, out);
}

// Round 15
// 339.572 us; speedup vs baseline: 1.6560x; 1.1993x over previous
//
#include <hip/hip_runtime.h>
#include <math.h>

#define DEV __device__ __forceinline__

DEV float lrelu(float v) { return v > 0.f ? v : 0.2f * v; }
DEV float4 ld4(const float* p) { return *reinterpret_cast<const float4*>(p); }

// ---------------- CSR build ----------------
__global__ void hist_kernel(const int* __restrict__ ei, int E, int* __restrict__ cnt) {
  int e = blockIdx.x * blockDim.x + threadIdx.x;
  if (e < E) atomicAdd(&cnt[ei[E + e]], 1);
}

__global__ __launch_bounds__(1024) void partial_kernel(const int* __restrict__ cnt, int N,
                                                       int* __restrict__ partials) {
  __shared__ int ws[16];
  int i = blockIdx.x * 1024 + threadIdx.x;
  int v = (i < N) ? cnt[i] : 0;
  #pragma unroll
  for (int off = 32; off >= 1; off >>= 1) v += __shfl_down(v, off);
  int lane = threadIdx.x & 63, wid = threadIdx.x >> 6;
  if (lane == 0) ws[wid] = v;
  __syncthreads();
  if (threadIdx.x < 64) {
    int t = (threadIdx.x < 16) ? ws[threadIdx.x] : 0;
    #pragma unroll
    for (int off = 8; off >= 1; off >>= 1) t += __shfl_down(t, off);
    if (threadIdx.x == 0) partials[blockIdx.x] = t;
  }
}

// cnt aliases cursor (each thread reads then writes only its own index) -> no __restrict__.
__global__ __launch_bounds__(1024) void apply_kernel(const int* cnt,
                                                     const int* __restrict__ partials,
                                                     int N, int* __restrict__ row_ptr,
                                                     int* cursor) {
  __shared__ int wsum[16];
  int off = 0;
  for (int i = 0; i < (int)blockIdx.x; ++i) off += partials[i];
  const int tid = threadIdx.x, lane = tid & 63, wid = tid >> 6;
  int i = blockIdx.x * 1024 + tid;
  int v = (i < N) ? cnt[i] : 0;
  int x = v;
  #pragma unroll
  for (int o = 1; o < 64; o <<= 1) {
    int y = __shfl_up(x, o);
    if (lane >= o) x += y;
  }
  if (lane == 63) wsum[wid] = x;
  __syncthreads();
  int woff = 0;
  for (int ww = 0; ww < wid; ++ww) woff += wsum[ww];
  int excl = off + woff + x - v;
  if (i < N) { row_ptr[i] = excl; cursor[i] = excl; }
  if (i == N - 1) row_ptr[N] = excl + v;
}

__global__ void scatter_kernel(const int* __restrict__ ei, int E,
                               int* __restrict__ cursor, int* __restrict__ csr_src) {
  int e = blockIdx.x * blockDim.x + threadIdx.x;
  if (e >= E) return;
  int s = ei[e], d = ei[E + e];
  int pos = atomicAdd(&cursor[d], 1);
  csr_src[pos] = s;
}

// ---------------- fused dual GEMM: Xl = A*Wl+bl, Xr = A*Wr+br ----------------
template <int K>
__global__ __launch_bounds__(256) void gemm_dual(
    const float* __restrict__ A, int N,
    const float* __restrict__ Wl, const float* __restrict__ bl,
    const float* __restrict__ Wr, const float* __restrict__ br,
    float* __restrict__ Xl, float* __restrict__ Xr) {
  constexpr int KC = 32;
  constexpr int BR = 128;
  constexpr int LDA = BR + 4;
  constexpr int LDW = 128 + 4;
  __shared__ float sA[KC][LDA];
  __shared__ float sW[KC][LDW];
  const int tid = threadIdx.x;
  const int rb = blockIdx.x * BR;
  const int rowg = tid >> 4;
  const int colg = tid & 15;
  float acc[8][8];
  #pragma unroll
  for (int i = 0; i < 8; ++i)
    #pragma unroll
    for (int j = 0; j < 8; ++j) acc[i][j] = 0.f;

  for (int kc = 0; kc < K; kc += KC) {
    #pragma unroll
    for (int rep = 0; rep < 4; ++rep) {
      int lin = rep * 1024 + tid * 4;
      int k = lin >> 7, j = lin & 127;
      const float* src = (j < 64) ? (Wl + (size_t)(kc + k) * 64 + j)
                                  : (Wr + (size_t)(kc + k) * 64 + (j - 64));
      *reinterpret_cast<float4*>(&sW[k][j]) = ld4(src);
    }
    #pragma unroll
    for (int rep = 0; rep < 4; ++rep) {
      int lin = rep * 1024 + tid * 4;
      int r = lin >> 5;
      int kk = lin & 31;
      int row = rb + r;
      if (row >= N) row = N - 1;
      float4 v = ld4(A + (size_t)row * K + kc + kk);
      sA[kk + 0][r] = v.x;
      sA[kk + 1][r] = v.y;
      sA[kk + 2][r] = v.z;
      sA[kk + 3][r] = v.w;
    }
    __syncthreads();
    #pragma unroll
    for (int k = 0; k < KC; ++k) {
      float a[8], wv[8];
      *reinterpret_cast<float4*>(&a[0]) = *reinterpret_cast<const float4*>(&sA[k][rowg * 8]);
      *reinterpret_cast<float4*>(&a[4]) = *reinterpret_cast<const float4*>(&sA[k][rowg * 8 + 4]);
      *reinterpret_cast<float4*>(&wv[0]) = *reinterpret_cast<const float4*>(&sW[k][colg * 8]);
      *reinterpret_cast<float4*>(&wv[4]) = *reinterpret_cast<const float4*>(&sW[k][colg * 8 + 4]);
      #pragma unroll
      for (int i = 0; i < 8; ++i)
        #pragma unroll
        for (int j = 0; j < 8; ++j) acc[i][j] = fmaf(a[i], wv[j], acc[i][j]);
    }
    __syncthreads();
  }
  const int cb = colg * 8;
  float bv[8];
  #pragma unroll
  for (int j = 0; j < 8; ++j) bv[j] = (cb < 64) ? bl[cb + j] : br[cb - 64 + j];
  #pragma unroll
  for (int i = 0; i < 8; ++i) {
    int row = rb + rowg * 8 + i;
    if (row < N) {
      float o[8];
      #pragma unroll
      for (int j = 0; j < 8; ++j) o[j] = acc[i][j] + bv[j];
      float* dst = (cb < 64) ? (Xl + (size_t)row * 64 + cb) : (Xr + (size_t)row * 64 + cb - 64);
      *reinterpret_cast<float4*>(dst) = make_float4(o[0], o[1], o[2], o[3]);
      *reinterpret_cast<float4*>(dst + 4) = make_float4(o[4], o[5], o[6], o[7]);
    }
  }
}

// ---------------- batched edge-block body with register-fold e-reduce ----------------
// 16 edges/batch. After the 4 fold rounds, lane l holds e_{l&15} reduced over its
// 16-lane group; FULL adds xor-16/32 rounds for the 64-lane (H=1) case.
// lim==16 from the main loop (constant-folded); tail passes lim<16.
template <bool FULL>
DEV void edge_batch(const float* __restrict__ xl, int sv, float xrc, float attc,
                    int c, int lim, float& m, float& s, float& acc) {
  float xv[16], u[16];
  #pragma unroll
  for (int j = 0; j < 16; ++j) {
    int sj = __shfl(sv, j);
    xv[j] = xl[(size_t)sj * 64 + c];
  }
  #pragma unroll
  for (int j = 0; j < 16; ++j) u[j] = lrelu(xv[j] + xrc) * attc;

  // fold rounds: 16 -> 8 -> 4 -> 2 -> 1 values, reducing across lanes
  #pragma unroll
  for (int k = 0; k < 8; ++k) {
    float a = u[2 * k], b = u[2 * k + 1];
    float mine = (c & 1) ? b : a, oth = (c & 1) ? a : b;
    u[k] = mine + __shfl_xor(oth, 1);
  }
  #pragma unroll
  for (int k = 0; k < 4; ++k) {
    float a = u[2 * k], b = u[2 * k + 1];
    float mine = (c & 2) ? b : a, oth = (c & 2) ? a : b;
    u[k] = mine + __shfl_xor(oth, 2);
  }
  #pragma unroll
  for (int k = 0; k < 2; ++k) {
    float a = u[2 * k], b = u[2 * k + 1];
    float mine = (c & 4) ? b : a, oth = (c & 4) ? a : b;
    u[k] = mine + __shfl_xor(oth, 4);
  }
  {
    float a = u[0], b = u[1];
    float mine = (c & 8) ? b : a, oth = (c & 8) ? a : b;
    u[0] = mine + __shfl_xor(oth, 8);
  }
  float ej = u[0];
  if (FULL) { ej += __shfl_xor(ej, 16); ej += __shfl_xor(ej, 32); }

  // masked batch max (group-reduce over 16 lanes)
  const bool valid = (c & 15) < lim;
  float bm = valid ? ej : -INFINITY;
  bm = fmaxf(bm, __shfl_xor(bm, 1));
  bm = fmaxf(bm, __shfl_xor(bm, 2));
  bm = fmaxf(bm, __shfl_xor(bm, 4));
  bm = fmaxf(bm, __shfl_xor(bm, 8));
  float mn = fmaxf(m, bm);
  float sc = __expf(m - mn);
  s *= sc; acc *= sc; m = mn;

  // single exp per lane; masked sum over the group
  float pj = valid ? __expf(ej - m) : 0.f;
  float ps = pj;
  ps += __shfl_xor(ps, 1);
  ps += __shfl_xor(ps, 2);
  ps += __shfl_xor(ps, 4);
  ps += __shfl_xor(ps, 8);
  s += ps;

  // broadcast p_j back and accumulate messages
  const int base = c & 48;
  #pragma unroll
  for (int j = 0; j < 16; ++j) {
    if (j < lim) {
      float p = __shfl(pj, base + j);
      acc = fmaf(p, xv[j], acc);
    }
  }
}

// ---------------- conv1 fused (H=4): edge logits + online softmax + aggregation ----------------
__global__ __launch_bounds__(256) void fused1_kernel(
    const int* __restrict__ row_ptr, const int* __restrict__ csr_src, int N,
    const float* __restrict__ xl, const float* __restrict__ xr,
    const float* __restrict__ att, const float* __restrict__ bias,
    float* __restrict__ out) {
  int n = blockIdx.x * 4 + (threadIdx.x >> 6);
  if (n >= N) return;
  const int c = threadIdx.x & 63;
  const float attc = att[c];
  const float xrc = xr[(size_t)n * 64 + c];
  const float xls = xl[(size_t)n * 64 + c];
  float t = lrelu(xls + xrc) * attc;
  t += __shfl_xor(t, 1); t += __shfl_xor(t, 2);
  t += __shfl_xor(t, 4); t += __shfl_xor(t, 8);
  float m = t;
  float s = 1.f;
  float acc = xls;

  const int p0 = row_ptr[n], p1 = row_ptr[n + 1];
  int p = p0;
  for (; p + 16 <= p1; p += 16) {
    int sv = csr_src[p + (c & 15)];
    edge_batch<false>(xl, sv, xrc, attc, c, 16, m, s, acc);
  }
  if (p < p1) {
    const int lim = p1 - p;
    int lidx = p + (c & 15); if (lidx >= p1) lidx = p1 - 1;
    int sv = csr_src[lidx];
    edge_batch<false>(xl, sv, xrc, attc, c, lim, m, s, acc);
  }
  float v = acc / s + bias[c];
  out[(size_t)n * 64 + c] = v > 0.f ? v : expm1f(v);  // fused ELU
}

// ---------------- conv2 fused (H=1) + bias2 + final linear 64->1 ----------------
__global__ __launch_bounds__(256) void fused2_kernel(
    const int* __restrict__ row_ptr, const int* __restrict__ csr_src, int N,
    const float* __restrict__ xl, const float* __restrict__ xr,
    const float* __restrict__ att, const float* __restrict__ bias,
    const float* __restrict__ Wlin, const float* __restrict__ blin,
    float* __restrict__ out) {
  int n = blockIdx.x * 4 + (threadIdx.x >> 6);
  if (n >= N) return;
  const int c = threadIdx.x & 63;
  const float attc = att[c];
  const float xrc = xr[(size_t)n * 64 + c];
  const float xls = xl[(size_t)n * 64 + c];
  float t = lrelu(xls + xrc) * attc;
  t += __shfl_xor(t, 1); t += __shfl_xor(t, 2); t += __shfl_xor(t, 4);
  t += __shfl_xor(t, 8); t += __shfl_xor(t, 16); t += __shfl_xor(t, 32);
  float m = t;
  float s = 1.f;
  float acc = xls;

  const int p0 = row_ptr[n], p1 = row_ptr[n + 1];
  int p = p0;
  for (; p + 16 <= p1; p += 16) {
    int sv = csr_src[p + (c & 15)];
    edge_batch<true>(xl, sv, xrc, attc, c, 16, m, s, acc);
  }
  if (p < p1) {
    const int lim = p1 - p;
    int lidx = p + (c & 15); if (lidx >= p1) lidx = p1 - 1;
    int sv = csr_src[lidx];
    edge_batch<true>(xl, sv, xrc, attc, c, lim, m, s, acc);
  }
  float y = (acc / s + bias[c]) * Wlin[c];
  y += __shfl_xor(y, 1); y += __shfl_xor(y, 2); y += __shfl_xor(y, 4);
  y += __shfl_xor(y, 8); y += __shfl_xor(y, 16); y += __shfl_xor(y, 32);
  if (c == 0) out[n] = y + blin[0];
}

// ---------------- launch ----------------
extern "C" void kernel_launch(void* const* d_in, const int* in_sizes, int n_in,
                              void* d_out, int out_size, void* d_ws, size_t ws_size,
                              hipStream_t stream) {
  const float* x     = (const float*)d_in[0];
  const int*   ei    = (const int*)d_in[1];
  const float* W1l   = (const float*)d_in[2];
  const float* b1l   = (const float*)d_in[3];
  const float* W1r   = (const float*)d_in[4];
  const float* b1r   = (const float*)d_in[5];
  const float* att1  = (const float*)d_in[6];
  const float* bias1 = (const float*)d_in[7];
  const float* W2l   = (const float*)d_in[8];
  const float* b2l   = (const float*)d_in[9];
  const float* W2r   = (const float*)d_in[10];
  const float* b2r   = (const float*)d_in[11];
  const float* att2  = (const float*)d_in[12];
  const float* bias2 = (const float*)d_in[13];
  const float* Wlin  = (const float*)d_in[14];
  const float* blin  = (const float*)d_in[15];
  float* out = (float*)d_out;

  const int Fin = 128;
  const int N = in_sizes[0] / Fin;
  const int E = in_sizes[1] / 2;

  char* w = (char*)d_ws;
  auto alloc = [&](size_t bytes) {
    char* p = w;
    w += (bytes + 255) & ~(size_t)255;
    return p;
  };
  float* xl1 = (float*)alloc((size_t)N * 64 * 4);
  float* xr1 = (float*)alloc((size_t)N * 64 * 4);
  float* h1  = (float*)alloc((size_t)N * 64 * 4);
  int* row_ptr  = (int*)alloc((size_t)(N + 1) * 4);
  int* cursor   = (int*)alloc((size_t)N * 4);
  int* partials = (int*)alloc((size_t)256 * 4);
  int* csr_src  = (int*)alloc((size_t)E * 4);
  // conv2 reuses conv1 buffers
  float* xl2 = xl1; float* xr2 = xr1;

  const int tpb = 256;
  const int nscan = (N + 1023) / 1024;

  // CSR build (reduce-then-scan)
  hipMemsetAsync(cursor, 0, (size_t)N * 4, stream);
  hist_kernel<<<(E + tpb - 1) / tpb, tpb, 0, stream>>>(ei, E, cursor);
  partial_kernel<<<nscan, 1024, 0, stream>>>(cursor, N, partials);
  apply_kernel<<<nscan, 1024, 0, stream>>>(cursor, partials, N, row_ptr, cursor);
  scatter_kernel<<<(E + tpb - 1) / tpb, tpb, 0, stream>>>(ei, E, cursor, csr_src);

  // conv1: dual GEMM + fused edge/softmax/aggregate (+ELU)
  gemm_dual<128><<<(N + 127) / 128, 256, 0, stream>>>(x, N, W1l, b1l, W1r, b1r, xl1, xr1);
  fused1_kernel<<<(N + 3) / 4, 256, 0, stream>>>(row_ptr, csr_src, N, xl1, xr1, att1, bias1, h1);

  // conv2: dual GEMM + fused (+final linear)
  gemm_dual<64><<<(N + 127) / 128, 256, 0, stream>>>(h1, N, W2l, b2l, W2r, b2r, xl2, xr2);
  fused2_kernel<<<(N + 3) / 4, 256, 0, stream>>>(row_ptr, csr_src, N, xl2, xr2, att2, bias2, Wlin, blin, out);
}